// Round 3
// baseline (384.779 us; speedup 1.0000x reference)
//
#include <hip/hip_runtime.h>
#include <cstdint>
#include <cstddef>

#define HIDDEN 1024
#define HEADS  16
#define DHEAD  64
#define BB     2
#define SS     2000
#define KNNR   20
#define MM     (BB*SS)   // 4000 rows

typedef __attribute__((ext_vector_type(8)))  short short8;
typedef __attribute__((ext_vector_type(4)))  float f32x4;
typedef __attribute__((ext_vector_type(16))) float f32x16;
typedef unsigned short ushort_t;
typedef unsigned int   uint_t;

#define LOG2E 1.4426950408889634f

__device__ __forceinline__ ushort_t f2bf(float f) {
    union { float f; uint_t u; } v; v.f = f;
    uint_t r = (v.u + 0x7FFFu + ((v.u >> 16) & 1u)) >> 16;
    return (ushort_t)r;
}
__device__ __forceinline__ float bf2f(ushort_t b) {
    union { uint_t u; float f; } v; v.u = ((uint_t)b) << 16;
    return v.f;
}

// ---------------------------------------------------------------------------
// grid-stride zero fill (graph-capture-safe replacement for hipMemsetAsync)
// ---------------------------------------------------------------------------
__global__ void zerofill_kernel(float* __restrict__ p, int n4)
{
    const int stride = gridDim.x * blockDim.x;
    for (int i = blockIdx.x * blockDim.x + threadIdx.x; i < n4; i += stride)
        *(float4*)(p + 4 * (size_t)i) = make_float4(0.f, 0.f, 0.f, 0.f);
}

// ---------------------------------------------------------------------------
// fp32 -> bf16 conversion kernels
// ---------------------------------------------------------------------------
__global__ void cvt3_kernel(const float* __restrict__ a, const float* __restrict__ b,
                            const float* __restrict__ c,
                            ushort_t* __restrict__ oa, ushort_t* __restrict__ ob,
                            ushort_t* __restrict__ oc, int n)
{
    const float* src; ushort_t* dst;
    if (blockIdx.y == 0)      { src = a; dst = oa; }
    else if (blockIdx.y == 1) { src = b; dst = ob; }
    else                      { src = c; dst = oc; }
    const int stride = gridDim.x * blockDim.x * 4;
    for (int i = (blockIdx.x * blockDim.x + threadIdx.x) * 4; i < n; i += stride) {
        float4 v = *(const float4*)(src + i);
        ushort_t o[4] = { f2bf(v.x), f2bf(v.y), f2bf(v.z), f2bf(v.w) };
        *(uint2*)(dst + i) = *(uint2*)o;
    }
}

__global__ void cvt4_kernel(const float* __restrict__ a, const float* __restrict__ b,
                            const float* __restrict__ c, const float* __restrict__ d,
                            ushort_t* __restrict__ oa, ushort_t* __restrict__ ob,
                            ushort_t* __restrict__ oc, ushort_t* __restrict__ od, int n)
{
    const float* src; ushort_t* dst;
    if (blockIdx.y == 0)      { src = a; dst = oa; }
    else if (blockIdx.y == 1) { src = b; dst = ob; }
    else if (blockIdx.y == 2) { src = c; dst = oc; }
    else                      { src = d; dst = od; }
    const int stride = gridDim.x * blockDim.x * 4;
    for (int i = (blockIdx.x * blockDim.x + threadIdx.x) * 4; i < n; i += stride) {
        float4 v = *(const float4*)(src + i);
        ushort_t o[4] = { f2bf(v.x), f2bf(v.y), f2bf(v.z), f2bf(v.w) };
        *(uint2*)(dst + i) = *(uint2*)o;
    }
}

// ---------------------------------------------------------------------------
// P[e][m] = dot(edge_emb[e], mask_emb[m])  (64x2 table)
// ---------------------------------------------------------------------------
__global__ void bias_table_kernel(const float* __restrict__ edge_emb,
                                  const float* __restrict__ mask_emb,
                                  float* __restrict__ P)
{
    const int e = blockIdx.x >> 1;
    const int m = blockIdx.x & 1;
    const int lane = threadIdx.x;
    const float* er = edge_emb + (size_t)e * HIDDEN;
    const float* mr = mask_emb + (size_t)m * HIDDEN;
    float s = 0.f;
    for (int d = lane; d < HIDDEN; d += 64) s += er[d] * mr[d];
    #pragma unroll
    for (int off = 32; off > 0; off >>= 1) s += __shfl_down(s, off, 64);
    if (lane == 0) P[e * 2 + m] = s;
}

// ---------------------------------------------------------------------------
// bf16 MFMA NT GEMM core: C_tile = A[m0:,kbeg:kend] @ Bw[n0:,kbeg:kend]^T
// 128x128 tile, BK=32, 4 waves (2x2), 4x4 frags of 16x16x32.
// OUT_MODE 1: bf16 store of (acc+bias)*oscale.  OUT_MODE 2: f32 atomicAdd of
// acc + (addbias?bias:0).
// ---------------------------------------------------------------------------
template<int OUT_MODE>
__device__ __forceinline__
void gemm_core(const ushort_t* __restrict__ A, const ushort_t* __restrict__ Bw,
               const float* __restrict__ bias, void* __restrict__ Cp,
               int M, int m0, int n0, int kbeg, int kend, float oscale, int addbias,
               ushort_t* As, ushort_t* Bs)
{
    const int t = threadIdx.x, l = t & 63, w = t >> 6;
    const int wr = w >> 1, wc = w & 1;
    const int g = l >> 4, r16 = l & 15;

    f32x4 acc[4][4];
    #pragma unroll
    for (int i = 0; i < 4; ++i)
        #pragma unroll
        for (int j = 0; j < 4; ++j)
            #pragma unroll
            for (int r = 0; r < 4; ++r) acc[i][j][r] = 0.f;

    for (int k0 = kbeg; k0 < kend; k0 += 32) {
        __syncthreads();
        #pragma unroll
        for (int i = 0; i < 2; ++i) {
            const int c = i * 256 + w * 64 + l;       // 16B chunk id
            const int row = c >> 2, kc = c & 3;
            int ra = m0 + row; ra = ra < M ? ra : M - 1;
            const ushort_t* srcA = A + (size_t)ra * 1024 + k0 + kc * 8;
            const ushort_t* srcB = Bw + (size_t)(n0 + row) * 1024 + k0 + kc * 8;
            __builtin_amdgcn_global_load_lds(
                (const __attribute__((address_space(1))) void*)srcA,
                (__attribute__((address_space(3))) void*)&As[(i * 256 + w * 64) * 8],
                16, 0, 0);
            __builtin_amdgcn_global_load_lds(
                (const __attribute__((address_space(1))) void*)srcB,
                (__attribute__((address_space(3))) void*)&Bs[(i * 256 + w * 64) * 8],
                16, 0, 0);
        }
        __syncthreads();

        short8 af[4], bf_[4];
        #pragma unroll
        for (int m = 0; m < 4; ++m)
            af[m] = *(const short8*)&As[(wr * 64 + m * 16 + r16) * 32 + g * 8];
        #pragma unroll
        for (int n = 0; n < 4; ++n)
            bf_[n] = *(const short8*)&Bs[(wc * 64 + n * 16 + r16) * 32 + g * 8];
        #pragma unroll
        for (int m = 0; m < 4; ++m)
            #pragma unroll
            for (int n = 0; n < 4; ++n)
                acc[m][n] = __builtin_amdgcn_mfma_f32_16x16x32_bf16(af[m], bf_[n], acc[m][n], 0, 0, 0);
    }

    float bv[4];
    #pragma unroll
    for (int n = 0; n < 4; ++n)
        bv[n] = addbias ? bias[n0 + wc * 64 + n * 16 + r16] : 0.f;

    #pragma unroll
    for (int m = 0; m < 4; ++m)
        #pragma unroll
        for (int n = 0; n < 4; ++n)
            #pragma unroll
            for (int r = 0; r < 4; ++r) {
                const int row = m0 + wr * 64 + m * 16 + g * 4 + r;
                const int col = n0 + wc * 64 + n * 16 + r16;
                if (row < M) {
                    if (OUT_MODE == 1) {
                        const float v = (acc[m][n][r] + bv[n]) * oscale;
                        ((ushort_t*)Cp)[(size_t)row * 1024 + col] = f2bf(v);
                    } else {
                        atomicAdd(&((float*)Cp)[(size_t)row * 1024 + col],
                                  acc[m][n][r] + bv[n]);
                    }
                }
            }
}

// Fused QKV projection: grid.x = 24 (8 col-tiles x 3 weights), grid.y = 32.
__global__ __launch_bounds__(256, 2)
void qkv_gemm(const ushort_t* __restrict__ qb, const ushort_t* __restrict__ kb,
              const ushort_t* __restrict__ vb,
              const ushort_t* __restrict__ Wq, const ushort_t* __restrict__ Wk,
              const ushort_t* __restrict__ Wv,
              const float* __restrict__ bq, const float* __restrict__ bk,
              const float* __restrict__ bv,
              ushort_t* __restrict__ qh, ushort_t* __restrict__ kh,
              ushort_t* __restrict__ vh)
{
    __shared__ __align__(16) ushort_t As[128 * 32];
    __shared__ __align__(16) ushort_t Bs[128 * 32];
    const int which = blockIdx.x >> 3;
    const int n0 = (blockIdx.x & 7) * 128, m0 = blockIdx.y * 128;
    const ushort_t* A; const ushort_t* Bw; const float* bias; ushort_t* dst;
    float osc = 1.f;
    if (which == 0)      { A = qb; Bw = Wq; bias = bq; dst = qh; osc = 0.125f * LOG2E; }
    else if (which == 1) { A = kb; Bw = Wk; bias = bk; dst = kh; }
    else                 { A = vb; Bw = Wv; bias = bv; dst = vh; }
    gemm_core<1>(A, Bw, bias, dst, MM, m0, n0, 0, 1024, osc, 1, As, Bs);
}

// Output projection, K-split x2 with fp32 atomic accumulation into d_out.
__global__ __launch_bounds__(256, 2)
void wo_gemm(const ushort_t* __restrict__ ctx, const ushort_t* __restrict__ Wo,
             const float* __restrict__ bo, float* __restrict__ out)
{
    __shared__ __align__(16) ushort_t As[128 * 32];
    __shared__ __align__(16) ushort_t Bs[128 * 32];
    const int z = blockIdx.z;
    gemm_core<2>(ctx, Wo, bo, out, MM, blockIdx.y * 128, blockIdx.x * 128,
                 z * 512, z * 512 + 512, 1.f, z == 0, As, Bs);
}

// ---------------------------------------------------------------------------
// vh [4000][1024] bf16 -> vhT [32 bh][64 d][2048 s] bf16 (zero-padded s)
// ---------------------------------------------------------------------------
__global__ __launch_bounds__(256)
void transpose_v(const ushort_t* __restrict__ vh, ushort_t* __restrict__ vhT)
{
    __shared__ __align__(16) ushort_t T[64 * 72];
    const int bh = blockIdx.y, b = bh >> 4, h = bh & 15;
    const int s0 = blockIdx.x * 64;
    const int t = threadIdx.x;
    #pragma unroll
    for (int i = 0; i < 2; ++i) {
        const int c = 2 * t + i, srow = c >> 3, d8 = c & 7;
        const int s = s0 + srow;
        uint4 val = make_uint4(0, 0, 0, 0);
        if (s < SS) val = *(const uint4*)(vh + (size_t)(b * SS + s) * 1024 + h * 64 + d8 * 8);
        *(uint4*)&T[srow * 72 + d8 * 8] = val;
    }
    __syncthreads();
    #pragma unroll
    for (int i = 0; i < 2; ++i) {
        const int c = 2 * t + i, drow = c >> 3, s8 = c & 7;
        ushort_t tmp[8];
        #pragma unroll
        for (int j = 0; j < 8; ++j) tmp[j] = T[(s8 * 8 + j) * 72 + drow];
        *(uint4*)(vhT + (size_t)(bh * 64 + drow) * 2048 + s0 + s8 * 8) = *(uint4*)tmp;
    }
}

// ---------------------------------------------------------------------------
// Fused MFMA attention, K-split x2 (blockIdx.z). Partial O accumulated with
// fp32 atomics into octx (pre-zeroed); per-z denoms to dpart. qh pre-scaled by
// 0.125*log2e -> softmax uses bare exp2f. Row-constant bias cancels; only
// db2 = (P1-P0)*log2e applied on c_mask==1 columns.
// ---------------------------------------------------------------------------
__global__ __launch_bounds__(256, 2)
void attn_mfma(const ushort_t* __restrict__ qh, const ushort_t* __restrict__ kh,
               const ushort_t* __restrict__ vhT, float* __restrict__ octx,
               float* __restrict__ dpart,
               const int* __restrict__ c_mask, const int* __restrict__ degrees,
               const float* __restrict__ P)
{
    __shared__ __align__(16) ushort_t Ks[64 * 72];
    __shared__ __align__(16) ushort_t Vt[64 * 72];
    __shared__ __align__(16) ushort_t Ps[4][32 * 72];
    __shared__ int cm[100];

    const int t = threadIdx.x, l = t & 63, w = t >> 6;
    const int lo = l & 31, hi = l >> 5;
    const int bh = blockIdx.y, b = bh >> 4, h = bh & 15;
    const int qw = blockIdx.x * 128 + w * 32;
    const int z = blockIdx.z;

    if (t < 100) cm[t] = c_mask[t];

    // Q A-fragments (4 K-steps of 16)
    short8 qf[4];
    {
        int qr = qw + lo; qr = qr < SS ? qr : SS - 1;
        const ushort_t* qp = qh + (size_t)(b * SS + qr) * 1024 + h * 64 + hi * 8;
        #pragma unroll
        for (int ks = 0; ks < 4; ++ks) qf[ks] = *(const short8*)(qp + ks * 16);
    }

    float db2[16], denom[16];
    #pragma unroll
    for (int r = 0; r < 16; ++r) {
        const int rp = (r & 3) + 8 * (r >> 2) + 4 * hi;
        int qr = qw + rp; qr = qr < SS ? qr : SS - 1;
        const int dv = degrees[qr / KNNR];
        db2[r] = (P[dv * 2 + 1] - P[dv * 2 + 0]) * LOG2E;
        denom[r] = 0.f;
    }

    f32x16 accO[2];
    #pragma unroll
    for (int n = 0; n < 2; ++n)
        #pragma unroll
        for (int i = 0; i < 16; ++i) accO[n][i] = 0.f;

    uint4 kreg[2], vreg[2];
    {   // preload first tile of this z-range
        #pragma unroll
        for (int i = 0; i < 2; ++i) {
            const int c = 2 * t + i, row = c >> 3, e8 = c & 7;
            int s = z * 1024 + row; s = s < SS ? s : SS - 1;
            kreg[i] = *(const uint4*)(kh + (size_t)(b * SS + s) * 1024 + h * 64 + e8 * 8);
            vreg[i] = *(const uint4*)(vhT + (size_t)(bh * 64 + row) * 2048 + z * 1024 + e8 * 8);
        }
    }

    for (int kt = 0; kt < 16; ++kt) {
        const int kt0 = (z * 16 + kt) * 64;
        __syncthreads();
        #pragma unroll
        for (int i = 0; i < 2; ++i) {
            const int c = 2 * t + i, row = c >> 3, e8 = c & 7;
            *(uint4*)&Ks[row * 72 + e8 * 8] = kreg[i];
            *(uint4*)&Vt[row * 72 + e8 * 8] = vreg[i];
        }
        if (kt < 15) {
            const int nt0 = kt0 + 64;
            #pragma unroll
            for (int i = 0; i < 2; ++i) {
                const int c = 2 * t + i, row = c >> 3, e8 = c & 7;
                int s = nt0 + row; s = s < SS ? s : SS - 1;
                kreg[i] = *(const uint4*)(kh + (size_t)(b * SS + s) * 1024 + h * 64 + e8 * 8);
                vreg[i] = *(const uint4*)(vhT + (size_t)(bh * 64 + row) * 2048 + nt0 + e8 * 8);
            }
        }
        __syncthreads();

        // ---- QK^T ----
        f32x16 sc[2];
        #pragma unroll
        for (int n = 0; n < 2; ++n)
            #pragma unroll
            for (int i = 0; i < 16; ++i) sc[n][i] = 0.f;
        #pragma unroll
        for (int ks = 0; ks < 4; ++ks)
            #pragma unroll
            for (int n = 0; n < 2; ++n) {
                const short8 kf = *(const short8*)&Ks[(n * 32 + lo) * 72 + ks * 16 + hi * 8];
                sc[n] = __builtin_amdgcn_mfma_f32_32x32x16_bf16(qf[ks], kf, sc[n], 0, 0, 0);
            }

        // ---- exp2 + bias + P-tile + denom partials ----
        int kb[2];
        #pragma unroll
        for (int n = 0; n < 2; ++n) {
            int col = kt0 + n * 32 + lo; col = col < SS ? col : SS - 1;
            kb[n] = cm[col / KNNR];
        }
        #pragma unroll
        for (int n = 0; n < 2; ++n)
            #pragma unroll
            for (int r = 0; r < 16; ++r) {
                const int rp = (r & 3) + 8 * (r >> 2) + 4 * hi;
                const float s = sc[n][r] + (kb[n] ? db2[r] : 0.0f);
                float e = exp2f(s);
                if (kt0 + n * 32 + lo >= SS) e = 0.f;
                const ushort_t pb = f2bf(e);
                denom[r] += bf2f(pb);
                Ps[w][rp * 72 + n * 32 + lo] = pb;
            }
        asm volatile("s_waitcnt lgkmcnt(0)" ::: "memory");
        __builtin_amdgcn_sched_barrier(0);

        // ---- PV ----
        #pragma unroll
        for (int ks = 0; ks < 4; ++ks) {
            const short8 pa = *(const short8*)&Ps[w][lo * 72 + ks * 16 + hi * 8];
            #pragma unroll
            for (int n = 0; n < 2; ++n) {
                const short8 vf = *(const short8*)&Vt[(n * 32 + lo) * 72 + ks * 16 + hi * 8];
                accO[n] = __builtin_amdgcn_mfma_f32_32x32x16_bf16(pa, vf, accO[n], 0, 0, 0);
            }
        }
    }

    // denom row-sums (across the 32-lane lo group), stored per z
    #pragma unroll
    for (int r = 0; r < 16; ++r) {
        float d = denom[r];
        d += __shfl_xor(d, 1);  d += __shfl_xor(d, 2);  d += __shfl_xor(d, 4);
        d += __shfl_xor(d, 8);  d += __shfl_xor(d, 16);
        if (lo == 0) {
            const int rp = (r & 3) + 8 * (r >> 2) + 4 * hi;
            const int qr = qw + rp;
            if (qr < SS) dpart[(size_t)z * 32 * SS + bh * SS + qr] = d;
        }
    }

    #pragma unroll
    for (int n = 0; n < 2; ++n)
        #pragma unroll
        for (int r = 0; r < 16; ++r) {
            const int rp = (r & 3) + 8 * (r >> 2) + 4 * hi;
            const int qr = qw + rp;
            if (qr < SS)
                atomicAdd(&octx[(size_t)(b * SS + qr) * 1024 + h * 64 + n * 32 + lo],
                          accO[n][r]);
        }
}

// ---------------------------------------------------------------------------
// ctx_bf16[i] = f2bf( octx[i] / (dpart0 + dpart1) )
// ---------------------------------------------------------------------------
__global__ __launch_bounds__(256)
void divide_kernel(const float* __restrict__ octx, const float* __restrict__ dpart,
                   ushort_t* __restrict__ ctx)
{
    const int i = (blockIdx.x * 256 + threadIdx.x) * 4;   // grid 4000 x 256 exact
    const int row = i >> 10, col = i & 1023;
    const int b = row >= SS ? 1 : 0;
    const int q = row - b * SS;
    const int h = col >> 6;
    const size_t di = (size_t)(b * 16 + h) * SS + q;
    const float inv = 1.f / (dpart[di] + dpart[32 * SS + di]);
    const float4 o = *(const float4*)(octx + i);
    ushort_t u[4] = { f2bf(o.x * inv), f2bf(o.y * inv), f2bf(o.z * inv), f2bf(o.w * inv) };
    *(uint2*)(ctx + i) = *(uint2*)u;
}

// ---------------------------------------------------------------------------
extern "C" void kernel_launch(void* const* d_in, const int* in_sizes, int n_in,
                              void* d_out, int out_size, void* d_ws, size_t ws_size,
                              hipStream_t stream)
{
    const int*   c_mask   = (const int*)  d_in[0];
    const int*   degrees  = (const int*)  d_in[1];
    const float* q        = (const float*)d_in[2];
    const float* k        = (const float*)d_in[3];
    const float* v        = (const float*)d_in[4];
    const float* Wq       = (const float*)d_in[5];
    const float* bq       = (const float*)d_in[6];
    const float* Wk       = (const float*)d_in[7];
    const float* bk       = (const float*)d_in[8];
    const float* Wv       = (const float*)d_in[9];
    const float* bv       = (const float*)d_in[10];
    const float* Wo       = (const float*)d_in[11];
    const float* bo       = (const float*)d_in[12];
    const float* edge_emb = (const float*)d_in[13];
    const float* mask_emb = (const float*)d_in[14];
    float* out = (float*)d_out;

    char* ws = (char*)d_ws;
    const size_t MiB = 1024 * 1024;
    ushort_t* qb   = (ushort_t*)(ws + 0 * MiB);
    ushort_t* kb_  = (ushort_t*)(ws + 8 * MiB);
    ushort_t* vb_  = (ushort_t*)(ws + 16 * MiB);
    ushort_t* Wqb  = (ushort_t*)(ws + 24 * MiB);
    ushort_t* Wkb  = (ushort_t*)(ws + 26 * MiB);
    ushort_t* Wvb  = (ushort_t*)(ws + 28 * MiB);
    ushort_t* Wob  = (ushort_t*)(ws + 30 * MiB);
    ushort_t* qhB  = (ushort_t*)(ws + 32 * MiB);
    ushort_t* khB  = (ushort_t*)(ws + 40 * MiB);
    ushort_t* vhB  = (ushort_t*)(ws + 48 * MiB);
    float*    octx = (float*)   (ws + 56 * MiB);                    // 16,384,000 B
    float*    dpart= (float*)   (ws + 56 * MiB + 16384000);         //    512,000 B
    float*    P    = (float*)   (ws + 73 * MiB);
    ushort_t* vhT  = kb_;   // kb consumed by QKV GEMM before transpose runs
    ushort_t* ctx  = qb;    // qb consumed by QKV GEMM before divide runs

    // zero O-accumulator + denom partials (contiguous), and d_out for Wo atomics
    zerofill_kernel<<<2048, 256, 0, stream>>>(octx, (16384000 + 512000) / 16);
    zerofill_kernel<<<2048, 256, 0, stream>>>(out, MM * HIDDEN / 4);

    cvt3_kernel<<<dim3(1024, 3), 256, 0, stream>>>(q, k, v, qb, kb_, vb_, MM * HIDDEN);
    cvt4_kernel<<<dim3(1024, 4), 256, 0, stream>>>(Wq, Wk, Wv, Wo, Wqb, Wkb, Wvb, Wob,
                                                   HIDDEN * HIDDEN);
    bias_table_kernel<<<dim3(128), dim3(64), 0, stream>>>(edge_emb, mask_emb, P);

    qkv_gemm<<<dim3(24, 32), 256, 0, stream>>>(qb, kb_, vb_, Wqb, Wkb, Wvb,
                                               bq, bk, bv, qhB, khB, vhB);

    transpose_v<<<dim3(32, 32), 256, 0, stream>>>(vhB, vhT);

    attn_mfma<<<dim3(16, 32, 2), 256, 0, stream>>>(qhB, khB, vhT, octx, dpart,
                                                   c_mask, degrees, P);

    divide_kernel<<<4000, 256, 0, stream>>>(octx, dpart, ctx);

    wo_gemm<<<dim3(8, 32, 2), 256, 0, stream>>>(ctx, Wob, bo, out);
}

// Round 7
// 336.831 us; speedup vs baseline: 1.1423x; 1.1423x over previous
//
#include <hip/hip_runtime.h>
#include <cstdint>
#include <cstddef>

#define HIDDEN 1024
#define HEADS  16
#define DHEAD  64
#define BB     2
#define SS     2000
#define KNNR   20
#define MM     (BB*SS)   // 4000 rows

typedef __attribute__((ext_vector_type(8)))  short short8;
typedef __attribute__((ext_vector_type(4)))  float f32x4;
typedef __attribute__((ext_vector_type(16))) float f32x16;
typedef unsigned short ushort_t;
typedef unsigned int   uint_t;

#define LOG2E 1.4426950408889634f

__device__ __forceinline__ ushort_t f2bf(float f) {
    union { float f; uint_t u; } v; v.f = f;
    uint_t r = (v.u + 0x7FFFu + ((v.u >> 16) & 1u)) >> 16;
    return (ushort_t)r;
}

__device__ __forceinline__ uint_t cvt_pk_bf16(float a, float b) {
    uint_t r;
    asm("v_cvt_pk_bf16_f32 %0, %1, %2" : "=v"(r) : "v"(a), "v"(b));
    return r;
}
__device__ __forceinline__ void plane_swap(uint_t& a, uint_t& b) {
    asm("v_permlane32_swap_b32 %0, %1" : "+v"(a), "+v"(b));
}

// ---------------------------------------------------------------------------
// fp32 -> bf16 conversion kernels
// ---------------------------------------------------------------------------
__global__ void cvt3_kernel(const float* __restrict__ a, const float* __restrict__ b,
                            const float* __restrict__ c,
                            ushort_t* __restrict__ oa, ushort_t* __restrict__ ob,
                            ushort_t* __restrict__ oc, int n)
{
    const float* src; ushort_t* dst;
    if (blockIdx.y == 0)      { src = a; dst = oa; }
    else if (blockIdx.y == 1) { src = b; dst = ob; }
    else                      { src = c; dst = oc; }
    const int stride = gridDim.x * blockDim.x * 4;
    for (int i = (blockIdx.x * blockDim.x + threadIdx.x) * 4; i < n; i += stride) {
        float4 v = *(const float4*)(src + i);
        ushort_t o[4] = { f2bf(v.x), f2bf(v.y), f2bf(v.z), f2bf(v.w) };
        *(uint2*)(dst + i) = *(uint2*)o;
    }
}

__global__ void cvt4_kernel(const float* __restrict__ a, const float* __restrict__ b,
                            const float* __restrict__ c, const float* __restrict__ d,
                            ushort_t* __restrict__ oa, ushort_t* __restrict__ ob,
                            ushort_t* __restrict__ oc, ushort_t* __restrict__ od, int n)
{
    const float* src; ushort_t* dst;
    if (blockIdx.y == 0)      { src = a; dst = oa; }
    else if (blockIdx.y == 1) { src = b; dst = ob; }
    else if (blockIdx.y == 2) { src = c; dst = oc; }
    else                      { src = d; dst = od; }
    const int stride = gridDim.x * blockDim.x * 4;
    for (int i = (blockIdx.x * blockDim.x + threadIdx.x) * 4; i < n; i += stride) {
        float4 v = *(const float4*)(src + i);
        ushort_t o[4] = { f2bf(v.x), f2bf(v.y), f2bf(v.z), f2bf(v.w) };
        *(uint2*)(dst + i) = *(uint2*)o;
    }
}

// ---------------------------------------------------------------------------
// P[e][m] = dot(edge_emb[e], mask_emb[m])  (64x2 table)
// ---------------------------------------------------------------------------
__global__ void bias_table_kernel(const float* __restrict__ edge_emb,
                                  const float* __restrict__ mask_emb,
                                  float* __restrict__ P)
{
    const int e = blockIdx.x >> 1;
    const int m = blockIdx.x & 1;
    const int lane = threadIdx.x;
    const float* er = edge_emb + (size_t)e * HIDDEN;
    const float* mr = mask_emb + (size_t)m * HIDDEN;
    float s = 0.f;
    for (int d = lane; d < HIDDEN; d += 64) s += er[d] * mr[d];
    #pragma unroll
    for (int off = 32; off > 0; off >>= 1) s += __shfl_down(s, off, 64);
    if (lane == 0) P[e * 2 + m] = s;
}

// ---------------------------------------------------------------------------
// bf16 MFMA NT GEMM core (m97 structure): 128x128 tile, BK=32, 4 waves (2x2),
// 4x4 frags of 16x16x32.  OUT_MODE 0: f32 store (+bias).  OUT_MODE 1: bf16
// store of (acc+bias)*oscale.
// ---------------------------------------------------------------------------
template<int OUT_MODE>
__device__ __forceinline__
void gemm_core(const ushort_t* __restrict__ A, const ushort_t* __restrict__ Bw,
               const float* __restrict__ bias, void* __restrict__ Cp,
               int M, int m0, int n0, float oscale,
               ushort_t* As, ushort_t* Bs)
{
    const int t = threadIdx.x, l = t & 63, w = t >> 6;
    const int wr = w >> 1, wc = w & 1;
    const int g = l >> 4, r16 = l & 15;

    f32x4 acc[4][4];
    #pragma unroll
    for (int i = 0; i < 4; ++i)
        #pragma unroll
        for (int j = 0; j < 4; ++j)
            #pragma unroll
            for (int r = 0; r < 4; ++r) acc[i][j][r] = 0.f;

    for (int k0 = 0; k0 < 1024; k0 += 32) {
        __syncthreads();
        #pragma unroll
        for (int i = 0; i < 2; ++i) {
            const int c = i * 256 + w * 64 + l;       // 16B chunk id
            const int row = c >> 2, kc = c & 3;
            int ra = m0 + row; ra = ra < M ? ra : M - 1;
            const ushort_t* srcA = A + (size_t)ra * 1024 + k0 + kc * 8;
            const ushort_t* srcB = Bw + (size_t)(n0 + row) * 1024 + k0 + kc * 8;
            __builtin_amdgcn_global_load_lds(
                (const __attribute__((address_space(1))) void*)srcA,
                (__attribute__((address_space(3))) void*)&As[(i * 256 + w * 64) * 8],
                16, 0, 0);
            __builtin_amdgcn_global_load_lds(
                (const __attribute__((address_space(1))) void*)srcB,
                (__attribute__((address_space(3))) void*)&Bs[(i * 256 + w * 64) * 8],
                16, 0, 0);
        }
        __syncthreads();

        short8 af[4], bf_[4];
        #pragma unroll
        for (int m = 0; m < 4; ++m)
            af[m] = *(const short8*)&As[(wr * 64 + m * 16 + r16) * 32 + g * 8];
        #pragma unroll
        for (int n = 0; n < 4; ++n)
            bf_[n] = *(const short8*)&Bs[(wc * 64 + n * 16 + r16) * 32 + g * 8];
        #pragma unroll
        for (int m = 0; m < 4; ++m)
            #pragma unroll
            for (int n = 0; n < 4; ++n)
                acc[m][n] = __builtin_amdgcn_mfma_f32_16x16x32_bf16(af[m], bf_[n], acc[m][n], 0, 0, 0);
    }

    float bv[4];
    #pragma unroll
    for (int n = 0; n < 4; ++n) bv[n] = bias[n0 + wc * 64 + n * 16 + r16];

    #pragma unroll
    for (int m = 0; m < 4; ++m)
        #pragma unroll
        for (int n = 0; n < 4; ++n)
            #pragma unroll
            for (int r = 0; r < 4; ++r) {
                const int row = m0 + wr * 64 + m * 16 + g * 4 + r;
                const int col = n0 + wc * 64 + n * 16 + r16;
                if (row < M) {
                    if (OUT_MODE == 1) {
                        const float v = (acc[m][n][r] + bv[n]) * oscale;
                        ((ushort_t*)Cp)[(size_t)row * 1024 + col] = f2bf(v);
                    } else {
                        ((float*)Cp)[(size_t)row * 1024 + col] = acc[m][n][r] + bv[n];
                    }
                }
            }
}

// Fused QKV projection: grid.x = 24 (8 col-tiles x 3 weights), grid.y = 32.
__global__ __launch_bounds__(256, 2)
void qkv_gemm(const ushort_t* __restrict__ qb, const ushort_t* __restrict__ kb,
              const ushort_t* __restrict__ vb,
              const ushort_t* __restrict__ Wq, const ushort_t* __restrict__ Wk,
              const ushort_t* __restrict__ Wv,
              const float* __restrict__ bq, const float* __restrict__ bk,
              const float* __restrict__ bv,
              ushort_t* __restrict__ qh, ushort_t* __restrict__ kh,
              ushort_t* __restrict__ vh)
{
    __shared__ __align__(16) ushort_t As[128 * 32];
    __shared__ __align__(16) ushort_t Bs[128 * 32];
    const int which = blockIdx.x >> 3;
    const int n0 = (blockIdx.x & 7) * 128, m0 = blockIdx.y * 128;
    const ushort_t* A; const ushort_t* Bw; const float* bias; ushort_t* dst;
    float osc = 1.f;
    if (which == 0)      { A = qb; Bw = Wq; bias = bq; dst = qh; osc = 0.125f * LOG2E; }
    else if (which == 1) { A = kb; Bw = Wk; bias = bk; dst = kh; }
    else                 { A = vb; Bw = Wv; bias = bv; dst = vh; }
    gemm_core<1>(A, Bw, bias, dst, MM, m0, n0, osc, As, Bs);
}

// Output projection: f32 out, full K, no atomics.
__global__ __launch_bounds__(256, 2)
void wo_gemm(const ushort_t* __restrict__ ctx, const ushort_t* __restrict__ Wo,
             const float* __restrict__ bo, float* __restrict__ out)
{
    __shared__ __align__(16) ushort_t As[128 * 32];
    __shared__ __align__(16) ushort_t Bs[128 * 32];
    gemm_core<0>(ctx, Wo, bo, out, MM, blockIdx.y * 128, blockIdx.x * 128, 1.f, As, Bs);
}

// ---------------------------------------------------------------------------
// vh [4000][1024] bf16 -> vhT [32 bh][64 d][2048 s] bf16 (zero-padded s)
// ---------------------------------------------------------------------------
__global__ __launch_bounds__(256)
void transpose_v(const ushort_t* __restrict__ vh, ushort_t* __restrict__ vhT)
{
    __shared__ __align__(16) ushort_t T[64 * 72];
    const int bh = blockIdx.y, b = bh >> 4, h = bh & 15;
    const int s0 = blockIdx.x * 64;
    const int t = threadIdx.x;
    #pragma unroll
    for (int i = 0; i < 2; ++i) {
        const int c = 2 * t + i, srow = c >> 3, d8 = c & 7;
        const int s = s0 + srow;
        uint4 val = make_uint4(0, 0, 0, 0);
        if (s < SS) val = *(const uint4*)(vh + (size_t)(b * SS + s) * 1024 + h * 64 + d8 * 8);
        *(uint4*)&T[srow * 72 + d8 * 8] = val;
    }
    __syncthreads();
    #pragma unroll
    for (int i = 0; i < 2; ++i) {
        const int c = 2 * t + i, drow = c >> 3, s8 = c & 7;
        ushort_t tmp[8];
        #pragma unroll
        for (int j = 0; j < 8; ++j) tmp[j] = T[(s8 * 8 + j) * 72 + drow];
        *(uint4*)(vhT + (size_t)(bh * 64 + drow) * 2048 + s0 + s8 * 8) = *(uint4*)tmp;
    }
}

// ---------------------------------------------------------------------------
// Fused MFMA attention, swapped-QK^T in-register-softmax version.
// Block = 4 waves x 32 q-rows = 128 q; k-tiles of 128 (2 halves of 64).
// QK^T computed as mfma(K, Q) -> lane holds P[q=lane&31][16 k]. exp2 in fp32,
// then cvt_pk_bf16 + permlane32_swap builds PV A-fragments in-register (no
// LDS round-trip, no barrier between QK and PV). Denom = in-lane adds +
// one shfl_xor(32). c_mask folded into a 2048-bit LDS bitmap.
// ---------------------------------------------------------------------------
__global__ __launch_bounds__(256, 2)
void attn_mfma(const ushort_t* __restrict__ qh, const ushort_t* __restrict__ kh,
               const ushort_t* __restrict__ vhT, ushort_t* __restrict__ ctx,
               const int* __restrict__ c_mask, const int* __restrict__ degrees,
               const float* __restrict__ P)
{
    __shared__ __align__(16) ushort_t Ks[128 * 72];
    __shared__ __align__(16) ushort_t Vt[64 * 136];
    __shared__ uint_t kmask[64];
    __shared__ float dnm[4][32];

    const int t = threadIdx.x, l = t & 63, w = t >> 6;
    const int lo = l & 31, hi = l >> 5;
    const int bh = blockIdx.y, b = bh >> 4, h = bh & 15;
    const int qw = blockIdx.x * 128 + w * 32;

    if (t < 64) {
        uint_t m = 0;
        #pragma unroll
        for (int j = 0; j < 32; ++j) {
            int idx = (t * 32 + j) / 20; idx = idx < 100 ? idx : 99;
            m |= (uint_t)(c_mask[idx] & 1) << j;
        }
        kmask[t] = m;
    }

    int qr = qw + lo; qr = qr < SS ? qr : SS - 1;
    short8 qf[4];
    {
        const ushort_t* qp = qh + (size_t)(b * SS + qr) * 1024 + h * 64 + hi * 8;
        #pragma unroll
        for (int ks = 0; ks < 4; ++ks) qf[ks] = *(const short8*)(qp + ks * 16);
    }
    const int dv = degrees[qr / KNNR];
    const float db = (P[dv * 2 + 1] - P[dv * 2 + 0]) * LOG2E;

    float denom = 0.f;
    f32x16 accO[2];
    #pragma unroll
    for (int n = 0; n < 2; ++n)
        #pragma unroll
        for (int i = 0; i < 16; ++i) accO[n][i] = 0.f;

    uint4 kreg[4], vreg[4];
    #pragma unroll
    for (int i = 0; i < 4; ++i) {
        const int c = i * 256 + t;
        int s = c >> 3; s = s < SS ? s : SS - 1;
        kreg[i] = *(const uint4*)(kh + (size_t)(b * SS + s) * 1024 + h * 64 + (c & 7) * 8);
        vreg[i] = *(const uint4*)(vhT + (size_t)(bh * 64 + (c >> 4)) * 2048 + (c & 15) * 8);
    }

    for (int kt = 0; kt < 16; ++kt) {
        const int kt0 = kt * 128;
        __syncthreads();
        #pragma unroll
        for (int i = 0; i < 4; ++i) {
            const int c = i * 256 + t;
            *(uint4*)&Ks[(c >> 3) * 72 + (c & 7) * 8] = kreg[i];
            *(uint4*)&Vt[(c >> 4) * 136 + (c & 15) * 8] = vreg[i];
        }
        if (kt < 15) {
            const int nb = kt0 + 128;
            #pragma unroll
            for (int i = 0; i < 4; ++i) {
                const int c = i * 256 + t;
                int s = nb + (c >> 3); s = s < SS ? s : SS - 1;
                kreg[i] = *(const uint4*)(kh + (size_t)(b * SS + s) * 1024 + h * 64 + (c & 7) * 8);
                vreg[i] = *(const uint4*)(vhT + (size_t)(bh * 64 + (c >> 4)) * 2048 + nb + (c & 15) * 8);
            }
        }
        __syncthreads();

        #pragma unroll
        for (int half = 0; half < 2; ++half) {
            const int kb0 = kt0 + half * 64;

            // ---- QK^T (swapped: A=K rows, B=Q cols) ----
            f32x16 sc[2];
            #pragma unroll
            for (int n = 0; n < 2; ++n)
                #pragma unroll
                for (int i = 0; i < 16; ++i) sc[n][i] = 0.f;
            #pragma unroll
            for (int ks = 0; ks < 4; ++ks)
                #pragma unroll
                for (int n = 0; n < 2; ++n) {
                    const short8 kf = *(const short8*)
                        &Ks[(half * 64 + n * 32 + lo) * 72 + ks * 16 + hi * 8];
                    sc[n] = __builtin_amdgcn_mfma_f32_32x32x16_bf16(kf, qf[ks], sc[n], 0, 0, 0);
                }

            // ---- exp2 + bias; build PV A-fragments in-register ----
            short8 pa[4];
            #pragma unroll
            for (int n = 0; n < 2; ++n) {
                const uint_t word = kmask[(kb0 + n * 32) >> 5];
                #pragma unroll
                for (int r = 0; r < 16; ++r) {
                    const int koff = (r & 3) + 8 * (r >> 2) + 4 * hi;
                    const int kcol = kb0 + n * 32 + koff;
                    const float s = sc[n][r] + (((word >> koff) & 1u) ? db : 0.f);
                    float e = exp2f(s);
                    e = (kcol < SS) ? e : 0.f;
                    denom += e;
                    sc[n][r] = e;
                }
                uint_t w0 = cvt_pk_bf16(sc[n][0], sc[n][1]);
                uint_t w2 = cvt_pk_bf16(sc[n][4], sc[n][5]);
                plane_swap(w0, w2);
                uint_t w1 = cvt_pk_bf16(sc[n][2], sc[n][3]);
                uint_t w3 = cvt_pk_bf16(sc[n][6], sc[n][7]);
                plane_swap(w1, w3);
                uint_t u0 = cvt_pk_bf16(sc[n][8],  sc[n][9]);
                uint_t u2 = cvt_pk_bf16(sc[n][12], sc[n][13]);
                plane_swap(u0, u2);
                uint_t u1 = cvt_pk_bf16(sc[n][10], sc[n][11]);
                uint_t u3 = cvt_pk_bf16(sc[n][14], sc[n][15]);
                plane_swap(u1, u3);
                union { uint_t u[4]; short8 s8v; } pk0, pk1;
                pk0.u[0] = w0; pk0.u[1] = w1; pk0.u[2] = w2; pk0.u[3] = w3;
                pk1.u[0] = u0; pk1.u[1] = u1; pk1.u[2] = u2; pk1.u[3] = u3;
                pa[2 * n]     = pk0.s8v;
                pa[2 * n + 1] = pk1.s8v;
            }

            // ---- PV ----
            #pragma unroll
            for (int ksp = 0; ksp < 4; ++ksp)
                #pragma unroll
                for (int no = 0; no < 2; ++no) {
                    const short8 vf = *(const short8*)
                        &Vt[(no * 32 + lo) * 136 + half * 64 + ksp * 16 + hi * 8];
                    accO[no] = __builtin_amdgcn_mfma_f32_32x32x16_bf16(pa[ksp], vf, accO[no], 0, 0, 0);
                }
        }
    }

    denom += __shfl_xor(denom, 32);
    if (hi == 0) dnm[w][lo] = denom;
    __syncthreads();

    #pragma unroll
    for (int r = 0; r < 16; ++r) {
        const int rp = (r & 3) + 8 * (r >> 2) + 4 * hi;
        const int q = qw + rp;
        if (q < SS) {
            const float inv = 1.f / dnm[w][rp];
            #pragma unroll
            for (int n = 0; n < 2; ++n)
                ctx[(size_t)(b * SS + q) * 1024 + h * 64 + n * 32 + lo] =
                    f2bf(accO[n][r] * inv);
        }
    }
}

// ---------------------------------------------------------------------------
extern "C" void kernel_launch(void* const* d_in, const int* in_sizes, int n_in,
                              void* d_out, int out_size, void* d_ws, size_t ws_size,
                              hipStream_t stream)
{
    const int*   c_mask   = (const int*)  d_in[0];
    const int*   degrees  = (const int*)  d_in[1];
    const float* q        = (const float*)d_in[2];
    const float* k        = (const float*)d_in[3];
    const float* v        = (const float*)d_in[4];
    const float* Wq       = (const float*)d_in[5];
    const float* bq       = (const float*)d_in[6];
    const float* Wk       = (const float*)d_in[7];
    const float* bk       = (const float*)d_in[8];
    const float* Wv       = (const float*)d_in[9];
    const float* bv       = (const float*)d_in[10];
    const float* Wo       = (const float*)d_in[11];
    const float* bo       = (const float*)d_in[12];
    const float* edge_emb = (const float*)d_in[13];
    const float* mask_emb = (const float*)d_in[14];
    float* out = (float*)d_out;

    char* ws = (char*)d_ws;
    const size_t MiB = 1024 * 1024;
    ushort_t* qb   = (ushort_t*)(ws + 0 * MiB);
    ushort_t* kb_  = (ushort_t*)(ws + 8 * MiB);
    ushort_t* vb_  = (ushort_t*)(ws + 16 * MiB);
    ushort_t* Wqb  = (ushort_t*)(ws + 24 * MiB);
    ushort_t* Wkb  = (ushort_t*)(ws + 26 * MiB);
    ushort_t* Wvb  = (ushort_t*)(ws + 28 * MiB);
    ushort_t* Wob  = (ushort_t*)(ws + 30 * MiB);
    ushort_t* qhB  = (ushort_t*)(ws + 32 * MiB);
    ushort_t* khB  = (ushort_t*)(ws + 40 * MiB);
    ushort_t* vhB  = (ushort_t*)(ws + 48 * MiB);
    float*    P    = (float*)   (ws + 56 * MiB);
    ushort_t* vhT  = kb_;   // kb consumed by QKV GEMM before transpose runs
    ushort_t* ctx  = qb;    // qb consumed by QKV GEMM before attn runs

    cvt3_kernel<<<dim3(1024, 3), 256, 0, stream>>>(q, k, v, qb, kb_, vb_, MM * HIDDEN);
    cvt4_kernel<<<dim3(1024, 4), 256, 0, stream>>>(Wq, Wk, Wv, Wo, Wqb, Wkb, Wvb, Wob,
                                                   HIDDEN * HIDDEN);
    bias_table_kernel<<<dim3(128), dim3(64), 0, stream>>>(edge_emb, mask_emb, P);

    qkv_gemm<<<dim3(24, 32), 256, 0, stream>>>(qb, kb_, vb_, Wqb, Wkb, Wvb,
                                               bq, bk, bv, qhB, khB, vhB);

    transpose_v<<<dim3(32, 32), 256, 0, stream>>>(vhB, vhT);

    attn_mfma<<<dim3(16, 32), 256, 0, stream>>>(qhB, khB, vhT, ctx, c_mask, degrees, P);

    wo_gemm<<<dim3(8, 32), 256, 0, stream>>>(ctx, Wob, bo, out);
}

// Round 10
// 336.208 us; speedup vs baseline: 1.1445x; 1.0019x over previous
//
#include <hip/hip_runtime.h>
#include <cstdint>
#include <cstddef>

#define HIDDEN 1024
#define HEADS  16
#define DHEAD  64
#define BB     2
#define SS     2000
#define KNNR   20
#define MM     (BB*SS)   // 4000 rows

typedef __attribute__((ext_vector_type(8)))  short short8;
typedef __attribute__((ext_vector_type(4)))  float f32x4;
typedef __attribute__((ext_vector_type(16))) float f32x16;
typedef unsigned short ushort_t;
typedef unsigned int   uint_t;
typedef __attribute__((ext_vector_type(4)))  uint_t   uintx4;
typedef __attribute__((ext_vector_type(4)))  ushort_t ushortx4;
typedef __attribute__((ext_vector_type(8)))  ushort_t ushortx8;

#define LOG2E 1.4426950408889634f

__device__ __forceinline__ ushort_t f2bf(float f) {
    union { float f; uint_t u; } v; v.f = f;
    uint_t r = (v.u + 0x7FFFu + ((v.u >> 16) & 1u)) >> 16;
    return (ushort_t)r;
}

__device__ __forceinline__ uint_t cvt_pk_bf16(float a, float b) {
    uint_t r;
    asm("v_cvt_pk_bf16_f32 %0, %1, %2" : "=v"(r) : "v"(a), "v"(b));
    return r;
}
__device__ __forceinline__ void plane_swap(uint_t& a, uint_t& b) {
    asm("v_permlane32_swap_b32 %0, %1" : "+v"(a), "+v"(b));
}

// ---------------------------------------------------------------------------
// fp32 -> bf16 conversion kernels (register-only packing, no stack arrays)
// ---------------------------------------------------------------------------
__global__ void cvt3_kernel(const float* __restrict__ a, const float* __restrict__ b,
                            const float* __restrict__ c,
                            ushort_t* __restrict__ oa, ushort_t* __restrict__ ob,
                            ushort_t* __restrict__ oc, int n)
{
    const float* src; ushort_t* dst;
    if (blockIdx.y == 0)      { src = a; dst = oa; }
    else if (blockIdx.y == 1) { src = b; dst = ob; }
    else                      { src = c; dst = oc; }
    const int stride = gridDim.x * blockDim.x * 4;
    for (int i = (blockIdx.x * blockDim.x + threadIdx.x) * 4; i < n; i += stride) {
        float4 v = *(const float4*)(src + i);
        ushortx4 o;
        o.x = f2bf(v.x); o.y = f2bf(v.y); o.z = f2bf(v.z); o.w = f2bf(v.w);
        *(ushortx4*)(dst + i) = o;
    }
}

__global__ void cvt4_kernel(const float* __restrict__ a, const float* __restrict__ b,
                            const float* __restrict__ c, const float* __restrict__ d,
                            ushort_t* __restrict__ oa, ushort_t* __restrict__ ob,
                            ushort_t* __restrict__ oc, ushort_t* __restrict__ od, int n)
{
    const float* src; ushort_t* dst;
    if (blockIdx.y == 0)      { src = a; dst = oa; }
    else if (blockIdx.y == 1) { src = b; dst = ob; }
    else if (blockIdx.y == 2) { src = c; dst = oc; }
    else                      { src = d; dst = od; }
    const int stride = gridDim.x * blockDim.x * 4;
    for (int i = (blockIdx.x * blockDim.x + threadIdx.x) * 4; i < n; i += stride) {
        float4 v = *(const float4*)(src + i);
        ushortx4 o;
        o.x = f2bf(v.x); o.y = f2bf(v.y); o.z = f2bf(v.z); o.w = f2bf(v.w);
        *(ushortx4*)(dst + i) = o;
    }
}

// ---------------------------------------------------------------------------
// P[e][m] = dot(edge_emb[e], mask_emb[m])  (64x2 table)
// ---------------------------------------------------------------------------
__global__ void bias_table_kernel(const float* __restrict__ edge_emb,
                                  const float* __restrict__ mask_emb,
                                  float* __restrict__ P)
{
    const int e = blockIdx.x >> 1;
    const int m = blockIdx.x & 1;
    const int lane = threadIdx.x;
    const float* er = edge_emb + (size_t)e * HIDDEN;
    const float* mr = mask_emb + (size_t)m * HIDDEN;
    float s = 0.f;
    for (int d = lane; d < HIDDEN; d += 64) s += er[d] * mr[d];
    #pragma unroll
    for (int off = 32; off > 0; off >>= 1) s += __shfl_down(s, off, 64);
    if (lane == 0) P[e * 2 + m] = s;
}

// ---------------------------------------------------------------------------
// bf16 MFMA NT GEMM core (m97 structure): 128x128 tile, BK=32, 4 waves (2x2),
// 4x4 frags of 16x16x32.  OUT_MODE 0: f32 store (+bias).  OUT_MODE 1: bf16
// store of (acc+bias)*oscale.
// ---------------------------------------------------------------------------
template<int OUT_MODE>
__device__ __forceinline__
void gemm_core(const ushort_t* __restrict__ A, const ushort_t* __restrict__ Bw,
               const float* __restrict__ bias, void* __restrict__ Cp,
               int M, int m0, int n0, float oscale,
               ushort_t* As, ushort_t* Bs)
{
    const int t = threadIdx.x, l = t & 63, w = t >> 6;
    const int wr = w >> 1, wc = w & 1;
    const int g = l >> 4, r16 = l & 15;

    f32x4 acc[4][4];
    #pragma unroll
    for (int i = 0; i < 4; ++i)
        #pragma unroll
        for (int j = 0; j < 4; ++j)
            #pragma unroll
            for (int r = 0; r < 4; ++r) acc[i][j][r] = 0.f;

    for (int k0 = 0; k0 < 1024; k0 += 32) {
        __syncthreads();
        #pragma unroll
        for (int i = 0; i < 2; ++i) {
            const int c = i * 256 + w * 64 + l;       // 16B chunk id
            const int row = c >> 2, kc = c & 3;
            int ra = m0 + row; ra = ra < M ? ra : M - 1;
            const ushort_t* srcA = A + (size_t)ra * 1024 + k0 + kc * 8;
            const ushort_t* srcB = Bw + (size_t)(n0 + row) * 1024 + k0 + kc * 8;
            __builtin_amdgcn_global_load_lds(
                (const __attribute__((address_space(1))) void*)srcA,
                (__attribute__((address_space(3))) void*)&As[(i * 256 + w * 64) * 8],
                16, 0, 0);
            __builtin_amdgcn_global_load_lds(
                (const __attribute__((address_space(1))) void*)srcB,
                (__attribute__((address_space(3))) void*)&Bs[(i * 256 + w * 64) * 8],
                16, 0, 0);
        }
        __syncthreads();

        short8 af[4], bf_[4];
        #pragma unroll
        for (int m = 0; m < 4; ++m)
            af[m] = *(const short8*)&As[(wr * 64 + m * 16 + r16) * 32 + g * 8];
        #pragma unroll
        for (int n = 0; n < 4; ++n)
            bf_[n] = *(const short8*)&Bs[(wc * 64 + n * 16 + r16) * 32 + g * 8];
        #pragma unroll
        for (int m = 0; m < 4; ++m)
            #pragma unroll
            for (int n = 0; n < 4; ++n)
                acc[m][n] = __builtin_amdgcn_mfma_f32_16x16x32_bf16(af[m], bf_[n], acc[m][n], 0, 0, 0);
    }

    float bv[4];
    #pragma unroll
    for (int n = 0; n < 4; ++n) bv[n] = bias[n0 + wc * 64 + n * 16 + r16];

    #pragma unroll
    for (int m = 0; m < 4; ++m)
        #pragma unroll
        for (int n = 0; n < 4; ++n)
            #pragma unroll
            for (int r = 0; r < 4; ++r) {
                const int row = m0 + wr * 64 + m * 16 + g * 4 + r;
                const int col = n0 + wc * 64 + n * 16 + r16;
                if (row < M) {
                    if (OUT_MODE == 1) {
                        const float v = (acc[m][n][r] + bv[n]) * oscale;
                        ((ushort_t*)Cp)[(size_t)row * 1024 + col] = f2bf(v);
                    } else {
                        ((float*)Cp)[(size_t)row * 1024 + col] = acc[m][n][r] + bv[n];
                    }
                }
            }
}

// Fused QKV projection: grid.x = 24 (8 col-tiles x 3 weights), grid.y = 32.
__global__ __launch_bounds__(256, 2)
void qkv_gemm(const ushort_t* __restrict__ qb, const ushort_t* __restrict__ kb,
              const ushort_t* __restrict__ vb,
              const ushort_t* __restrict__ Wq, const ushort_t* __restrict__ Wk,
              const ushort_t* __restrict__ Wv,
              const float* __restrict__ bq, const float* __restrict__ bk,
              const float* __restrict__ bv,
              ushort_t* __restrict__ qh, ushort_t* __restrict__ kh,
              ushort_t* __restrict__ vh)
{
    __shared__ __align__(16) ushort_t As[128 * 32];
    __shared__ __align__(16) ushort_t Bs[128 * 32];
    const int which = blockIdx.x >> 3;
    const int n0 = (blockIdx.x & 7) * 128, m0 = blockIdx.y * 128;
    const ushort_t* A; const ushort_t* Bw; const float* bias; ushort_t* dst;
    float osc = 1.f;
    if (which == 0)      { A = qb; Bw = Wq; bias = bq; dst = qh; osc = 0.125f * LOG2E; }
    else if (which == 1) { A = kb; Bw = Wk; bias = bk; dst = kh; }
    else                 { A = vb; Bw = Wv; bias = bv; dst = vh; }
    gemm_core<1>(A, Bw, bias, dst, MM, m0, n0, osc, As, Bs);
}

// Output projection: f32 out, full K, no atomics.
__global__ __launch_bounds__(256, 2)
void wo_gemm(const ushort_t* __restrict__ ctx, const ushort_t* __restrict__ Wo,
             const float* __restrict__ bo, float* __restrict__ out)
{
    __shared__ __align__(16) ushort_t As[128 * 32];
    __shared__ __align__(16) ushort_t Bs[128 * 32];
    gemm_core<0>(ctx, Wo, bo, out, MM, blockIdx.y * 128, blockIdx.x * 128, 1.f, As, Bs);
}

// ---------------------------------------------------------------------------
// vh [4000][1024] bf16 -> vhT [32 bh][64 d][2048 s] bf16 (zero-padded s)
// ---------------------------------------------------------------------------
__global__ __launch_bounds__(256)
void transpose_v(const ushort_t* __restrict__ vh, ushort_t* __restrict__ vhT)
{
    __shared__ __align__(16) ushort_t T[64 * 72];
    const int bh = blockIdx.y, b = bh >> 4, h = bh & 15;
    const int s0 = blockIdx.x * 64;
    const int t = threadIdx.x;
    #pragma unroll
    for (int i = 0; i < 2; ++i) {
        const int c = 2 * t + i, srow = c >> 3, d8 = c & 7;
        const int s = s0 + srow;
        uint4 val = make_uint4(0, 0, 0, 0);
        if (s < SS) val = *(const uint4*)(vh + (size_t)(b * SS + s) * 1024 + h * 64 + d8 * 8);
        *(uint4*)&T[srow * 72 + d8 * 8] = val;
    }
    __syncthreads();
    #pragma unroll
    for (int i = 0; i < 2; ++i) {
        const int c = 2 * t + i, drow = c >> 3, s8 = c & 7;
        ushortx8 tmp;
        #pragma unroll
        for (int j = 0; j < 8; ++j) tmp[j] = T[(s8 * 8 + j) * 72 + drow];
        *(ushortx8*)(vhT + (size_t)(bh * 64 + drow) * 2048 + s0 + s8 * 8) = tmp;
    }
}

// ---------------------------------------------------------------------------
// Fused MFMA attention, swapped-QK^T in-register-softmax version.
// Block = 4 waves x 32 q-rows = 128 q; k-tiles of 128 (2 halves of 64).
// QK^T computed as mfma(K, Q) -> lane holds P[q=lane&31][16 k]. exp2 in fp32,
// then cvt_pk_bf16 + permlane32_swap builds PV A-fragments IN REGISTERS
// (ext_vector inserts + bit_cast -- NO unions/stack aggregates, which scratch-
// spilled in R7: 254MB HBM writes). Denom = in-lane adds + one shfl_xor(32).
// c_mask folded into a 2048-bit LDS bitmap.
// ---------------------------------------------------------------------------
__global__ __launch_bounds__(256, 2)
void attn_mfma(const ushort_t* __restrict__ qh, const ushort_t* __restrict__ kh,
               const ushort_t* __restrict__ vhT, ushort_t* __restrict__ ctx,
               const int* __restrict__ c_mask, const int* __restrict__ degrees,
               const float* __restrict__ P)
{
    __shared__ __align__(16) ushort_t Ks[128 * 72];
    __shared__ __align__(16) ushort_t Vt[64 * 136];
    __shared__ uint_t kmask[64];
    __shared__ float dnm[4][32];

    const int t = threadIdx.x, l = t & 63, w = t >> 6;
    const int lo = l & 31, hi = l >> 5;
    const int bh = blockIdx.y, b = bh >> 4, h = bh & 15;
    const int qw = blockIdx.x * 128 + w * 32;

    if (t < 64) {
        uint_t m = 0;
        #pragma unroll
        for (int j = 0; j < 32; ++j) {
            int idx = (t * 32 + j) / 20; idx = idx < 100 ? idx : 99;
            m |= (uint_t)(c_mask[idx] & 1) << j;
        }
        kmask[t] = m;
    }

    int qr = qw + lo; qr = qr < SS ? qr : SS - 1;
    short8 qf[4];
    {
        const ushort_t* qp = qh + (size_t)(b * SS + qr) * 1024 + h * 64 + hi * 8;
        #pragma unroll
        for (int ks = 0; ks < 4; ++ks) qf[ks] = *(const short8*)(qp + ks * 16);
    }
    const int dv = degrees[qr / KNNR];
    const float db = (P[dv * 2 + 1] - P[dv * 2 + 0]) * LOG2E;

    float denom = 0.f;
    f32x16 accO[2];
    #pragma unroll
    for (int n = 0; n < 2; ++n)
        #pragma unroll
        for (int i = 0; i < 16; ++i) accO[n][i] = 0.f;

    uint4 kreg[4], vreg[4];
    #pragma unroll
    for (int i = 0; i < 4; ++i) {
        const int c = i * 256 + t;
        int s = c >> 3; s = s < SS ? s : SS - 1;
        kreg[i] = *(const uint4*)(kh + (size_t)(b * SS + s) * 1024 + h * 64 + (c & 7) * 8);
        vreg[i] = *(const uint4*)(vhT + (size_t)(bh * 64 + (c >> 4)) * 2048 + (c & 15) * 8);
    }

    for (int kt = 0; kt < 16; ++kt) {
        const int kt0 = kt * 128;
        __syncthreads();
        #pragma unroll
        for (int i = 0; i < 4; ++i) {
            const int c = i * 256 + t;
            *(uint4*)&Ks[(c >> 3) * 72 + (c & 7) * 8] = kreg[i];
            *(uint4*)&Vt[(c >> 4) * 136 + (c & 15) * 8] = vreg[i];
        }
        if (kt < 15) {
            const int nb = kt0 + 128;
            #pragma unroll
            for (int i = 0; i < 4; ++i) {
                const int c = i * 256 + t;
                int s = nb + (c >> 3); s = s < SS ? s : SS - 1;
                kreg[i] = *(const uint4*)(kh + (size_t)(b * SS + s) * 1024 + h * 64 + (c & 7) * 8);
                vreg[i] = *(const uint4*)(vhT + (size_t)(bh * 64 + (c >> 4)) * 2048 + nb + (c & 15) * 8);
            }
        }
        __syncthreads();

        #pragma unroll
        for (int half = 0; half < 2; ++half) {
            const int kb0 = kt0 + half * 64;

            // ---- QK^T (swapped: A=K rows, B=Q cols) ----
            f32x16 sc[2];
            #pragma unroll
            for (int n = 0; n < 2; ++n)
                #pragma unroll
                for (int i = 0; i < 16; ++i) sc[n][i] = 0.f;
            #pragma unroll
            for (int ks = 0; ks < 4; ++ks)
                #pragma unroll
                for (int n = 0; n < 2; ++n) {
                    const short8 kf = *(const short8*)
                        &Ks[(half * 64 + n * 32 + lo) * 72 + ks * 16 + hi * 8];
                    sc[n] = __builtin_amdgcn_mfma_f32_32x32x16_bf16(kf, qf[ks], sc[n], 0, 0, 0);
                }

            // ---- exp2 + bias; build PV A-fragments in registers ----
            short8 pa[4];
            #pragma unroll
            for (int n = 0; n < 2; ++n) {
                const uint_t word = kmask[(kb0 + n * 32) >> 5];
                #pragma unroll
                for (int r = 0; r < 16; ++r) {
                    const int koff = (r & 3) + 8 * (r >> 2) + 4 * hi;
                    const int kcol = kb0 + n * 32 + koff;
                    const float s = sc[n][r] + (((word >> koff) & 1u) ? db : 0.f);
                    float e = exp2f(s);
                    e = (kcol < SS) ? e : 0.f;
                    denom += e;
                    sc[n][r] = e;
                }
                uint_t w0 = cvt_pk_bf16(sc[n][0], sc[n][1]);
                uint_t w2 = cvt_pk_bf16(sc[n][4], sc[n][5]);
                plane_swap(w0, w2);
                uint_t w1 = cvt_pk_bf16(sc[n][2], sc[n][3]);
                uint_t w3 = cvt_pk_bf16(sc[n][6], sc[n][7]);
                plane_swap(w1, w3);
                uint_t u0 = cvt_pk_bf16(sc[n][8],  sc[n][9]);
                uint_t u2 = cvt_pk_bf16(sc[n][12], sc[n][13]);
                plane_swap(u0, u2);
                uint_t u1 = cvt_pk_bf16(sc[n][10], sc[n][11]);
                uint_t u3 = cvt_pk_bf16(sc[n][14], sc[n][15]);
                plane_swap(u1, u3);
                uintx4 pk0, pk1;
                pk0.x = w0; pk0.y = w1; pk0.z = w2; pk0.w = w3;
                pk1.x = u0; pk1.y = u1; pk1.z = u2; pk1.w = u3;
                pa[2 * n]     = __builtin_bit_cast(short8, pk0);
                pa[2 * n + 1] = __builtin_bit_cast(short8, pk1);
            }

            // ---- PV ----
            #pragma unroll
            for (int ksp = 0; ksp < 4; ++ksp)
                #pragma unroll
                for (int no = 0; no < 2; ++no) {
                    const short8 vf = *(const short8*)
                        &Vt[(no * 32 + lo) * 136 + half * 64 + ksp * 16 + hi * 8];
                    accO[no] = __builtin_amdgcn_mfma_f32_32x32x16_bf16(pa[ksp], vf, accO[no], 0, 0, 0);
                }
        }
    }

    denom += __shfl_xor(denom, 32);
    if (hi == 0) dnm[w][lo] = denom;
    __syncthreads();

    #pragma unroll
    for (int r = 0; r < 16; ++r) {
        const int rp = (r & 3) + 8 * (r >> 2) + 4 * hi;
        const int q = qw + rp;
        if (q < SS) {
            const float inv = 1.f / dnm[w][rp];
            #pragma unroll
            for (int n = 0; n < 2; ++n)
                ctx[(size_t)(b * SS + q) * 1024 + h * 64 + n * 32 + lo] =
                    f2bf(accO[n][r] * inv);
        }
    }
}

// ---------------------------------------------------------------------------
extern "C" void kernel_launch(void* const* d_in, const int* in_sizes, int n_in,
                              void* d_out, int out_size, void* d_ws, size_t ws_size,
                              hipStream_t stream)
{
    const int*   c_mask   = (const int*)  d_in[0];
    const int*   degrees  = (const int*)  d_in[1];
    const float* q        = (const float*)d_in[2];
    const float* k        = (const float*)d_in[3];
    const float* v        = (const float*)d_in[4];
    const float* Wq       = (const float*)d_in[5];
    const float* bq       = (const float*)d_in[6];
    const float* Wk       = (const float*)d_in[7];
    const float* bk       = (const float*)d_in[8];
    const float* Wv       = (const float*)d_in[9];
    const float* bv       = (const float*)d_in[10];
    const float* Wo       = (const float*)d_in[11];
    const float* bo       = (const float*)d_in[12];
    const float* edge_emb = (const float*)d_in[13];
    const float* mask_emb = (const float*)d_in[14];
    float* out = (float*)d_out;

    char* ws = (char*)d_ws;
    const size_t MiB = 1024 * 1024;
    ushort_t* qb   = (ushort_t*)(ws + 0 * MiB);
    ushort_t* kb_  = (ushort_t*)(ws + 8 * MiB);
    ushort_t* vb_  = (ushort_t*)(ws + 16 * MiB);
    ushort_t* Wqb  = (ushort_t*)(ws + 24 * MiB);
    ushort_t* Wkb  = (ushort_t*)(ws + 26 * MiB);
    ushort_t* Wvb  = (ushort_t*)(ws + 28 * MiB);
    ushort_t* Wob  = (ushort_t*)(ws + 30 * MiB);
    ushort_t* qhB  = (ushort_t*)(ws + 32 * MiB);
    ushort_t* khB  = (ushort_t*)(ws + 40 * MiB);
    ushort_t* vhB  = (ushort_t*)(ws + 48 * MiB);
    float*    P    = (float*)   (ws + 56 * MiB);
    ushort_t* vhT  = kb_;   // kb consumed by QKV GEMM before transpose runs
    ushort_t* ctx  = qb;    // qb consumed by QKV GEMM before attn runs

    cvt3_kernel<<<dim3(1024, 3), 256, 0, stream>>>(q, k, v, qb, kb_, vb_, MM * HIDDEN);
    cvt4_kernel<<<dim3(1024, 4), 256, 0, stream>>>(Wq, Wk, Wv, Wo, Wqb, Wkb, Wvb, Wob,
                                                   HIDDEN * HIDDEN);
    bias_table_kernel<<<dim3(128), dim3(64), 0, stream>>>(edge_emb, mask_emb, P);

    qkv_gemm<<<dim3(24, 32), 256, 0, stream>>>(qb, kb_, vb_, Wqb, Wkb, Wvb,
                                               bq, bk, bv, qhB, khB, vhB);

    transpose_v<<<dim3(32, 32), 256, 0, stream>>>(vhB, vhT);

    attn_mfma<<<dim3(16, 32), 256, 0, stream>>>(qhB, khB, vhT, ctx, c_mask, degrees, P);

    wo_gemm<<<dim3(8, 32), 256, 0, stream>>>(ctx, Wob, bo, out);
}

// Round 11
// 278.120 us; speedup vs baseline: 1.3835x; 1.2089x over previous
//
#include <hip/hip_runtime.h>
#include <cstdint>
#include <cstddef>

#define HIDDEN 1024
#define HEADS  16
#define DHEAD  64
#define BB     2
#define SS     2000
#define KNNR   20
#define MM     (BB*SS)   // 4000 rows

typedef __attribute__((ext_vector_type(8)))  short short8;
typedef __attribute__((ext_vector_type(4)))  float f32x4;
typedef __attribute__((ext_vector_type(16))) float f32x16;
typedef unsigned short ushort_t;
typedef unsigned int   uint_t;
typedef __attribute__((ext_vector_type(4)))  uint_t   uintx4;
typedef __attribute__((ext_vector_type(4)))  ushort_t ushortx4;
typedef __attribute__((ext_vector_type(8)))  ushort_t ushortx8;

#define LOG2E 1.4426950408889634f
#define AS1 __attribute__((address_space(1)))
#define AS3 __attribute__((address_space(3)))

__device__ __forceinline__ ushort_t f2bf(float f) {
    union { float f; uint_t u; } v; v.f = f;
    uint_t r = (v.u + 0x7FFFu + ((v.u >> 16) & 1u)) >> 16;
    return (ushort_t)r;
}

__device__ __forceinline__ uint_t cvt_pk_bf16(float a, float b) {
    uint_t r;
    asm("v_cvt_pk_bf16_f32 %0, %1, %2" : "=v"(r) : "v"(a), "v"(b));
    return r;
}
__device__ __forceinline__ void plane_swap(uint_t& a, uint_t& b) {
    asm("v_permlane32_swap_b32 %0, %1" : "+v"(a), "+v"(b));
}

// ---------------------------------------------------------------------------
// fp32 -> bf16 conversion kernels
// ---------------------------------------------------------------------------
__global__ void cvt3_kernel(const float* __restrict__ a, const float* __restrict__ b,
                            const float* __restrict__ c,
                            ushort_t* __restrict__ oa, ushort_t* __restrict__ ob,
                            ushort_t* __restrict__ oc, int n)
{
    const float* src; ushort_t* dst;
    if (blockIdx.y == 0)      { src = a; dst = oa; }
    else if (blockIdx.y == 1) { src = b; dst = ob; }
    else                      { src = c; dst = oc; }
    const int stride = gridDim.x * blockDim.x * 4;
    for (int i = (blockIdx.x * blockDim.x + threadIdx.x) * 4; i < n; i += stride) {
        float4 v = *(const float4*)(src + i);
        ushortx4 o;
        o.x = f2bf(v.x); o.y = f2bf(v.y); o.z = f2bf(v.z); o.w = f2bf(v.w);
        *(ushortx4*)(dst + i) = o;
    }
}

__global__ void cvt4_kernel(const float* __restrict__ a, const float* __restrict__ b,
                            const float* __restrict__ c, const float* __restrict__ d,
                            ushort_t* __restrict__ oa, ushort_t* __restrict__ ob,
                            ushort_t* __restrict__ oc, ushort_t* __restrict__ od, int n)
{
    const float* src; ushort_t* dst;
    if (blockIdx.y == 0)      { src = a; dst = oa; }
    else if (blockIdx.y == 1) { src = b; dst = ob; }
    else if (blockIdx.y == 2) { src = c; dst = oc; }
    else                      { src = d; dst = od; }
    const int stride = gridDim.x * blockDim.x * 4;
    for (int i = (blockIdx.x * blockDim.x + threadIdx.x) * 4; i < n; i += stride) {
        float4 v = *(const float4*)(src + i);
        ushortx4 o;
        o.x = f2bf(v.x); o.y = f2bf(v.y); o.z = f2bf(v.z); o.w = f2bf(v.w);
        *(ushortx4*)(dst + i) = o;
    }
}

// ---------------------------------------------------------------------------
// P[e][m] = dot(edge_emb[e], mask_emb[m])  (64x2 table)
// ---------------------------------------------------------------------------
__global__ void bias_table_kernel(const float* __restrict__ edge_emb,
                                  const float* __restrict__ mask_emb,
                                  float* __restrict__ P)
{
    const int e = blockIdx.x >> 1;
    const int m = blockIdx.x & 1;
    const int lane = threadIdx.x;
    const float* er = edge_emb + (size_t)e * HIDDEN;
    const float* mr = mask_emb + (size_t)m * HIDDEN;
    float s = 0.f;
    for (int d = lane; d < HIDDEN; d += 64) s += er[d] * mr[d];
    #pragma unroll
    for (int off = 32; off > 0; off >>= 1) s += __shfl_down(s, off, 64);
    if (lane == 0) P[e * 2 + m] = s;
}

// ---------------------------------------------------------------------------
// bf16 MFMA NT GEMM core (m97 structure): 128x128 tile, BK=32, 4 waves (2x2),
// 4x4 frags of 16x16x32.
// ---------------------------------------------------------------------------
template<int OUT_MODE>
__device__ __forceinline__
void gemm_core(const ushort_t* __restrict__ A, const ushort_t* __restrict__ Bw,
               const float* __restrict__ bias, void* __restrict__ Cp,
               int M, int m0, int n0, float oscale,
               ushort_t* As, ushort_t* Bs)
{
    const int t = threadIdx.x, l = t & 63, w = t >> 6;
    const int wr = w >> 1, wc = w & 1;
    const int g = l >> 4, r16 = l & 15;

    f32x4 acc[4][4];
    #pragma unroll
    for (int i = 0; i < 4; ++i)
        #pragma unroll
        for (int j = 0; j < 4; ++j)
            #pragma unroll
            for (int r = 0; r < 4; ++r) acc[i][j][r] = 0.f;

    for (int k0 = 0; k0 < 1024; k0 += 32) {
        __syncthreads();
        #pragma unroll
        for (int i = 0; i < 2; ++i) {
            const int c = i * 256 + w * 64 + l;       // 16B chunk id
            const int row = c >> 2, kc = c & 3;
            int ra = m0 + row; ra = ra < M ? ra : M - 1;
            const ushort_t* srcA = A + (size_t)ra * 1024 + k0 + kc * 8;
            const ushort_t* srcB = Bw + (size_t)(n0 + row) * 1024 + k0 + kc * 8;
            __builtin_amdgcn_global_load_lds(
                (const AS1 void*)srcA, (AS3 void*)&As[(i * 256 + w * 64) * 8],
                16, 0, 0);
            __builtin_amdgcn_global_load_lds(
                (const AS1 void*)srcB, (AS3 void*)&Bs[(i * 256 + w * 64) * 8],
                16, 0, 0);
        }
        __syncthreads();

        short8 af[4], bf_[4];
        #pragma unroll
        for (int m = 0; m < 4; ++m)
            af[m] = *(const short8*)&As[(wr * 64 + m * 16 + r16) * 32 + g * 8];
        #pragma unroll
        for (int n = 0; n < 4; ++n)
            bf_[n] = *(const short8*)&Bs[(wc * 64 + n * 16 + r16) * 32 + g * 8];
        #pragma unroll
        for (int m = 0; m < 4; ++m)
            #pragma unroll
            for (int n = 0; n < 4; ++n)
                acc[m][n] = __builtin_amdgcn_mfma_f32_16x16x32_bf16(af[m], bf_[n], acc[m][n], 0, 0, 0);
    }

    float bv[4];
    #pragma unroll
    for (int n = 0; n < 4; ++n) bv[n] = bias[n0 + wc * 64 + n * 16 + r16];

    #pragma unroll
    for (int m = 0; m < 4; ++m)
        #pragma unroll
        for (int n = 0; n < 4; ++n)
            #pragma unroll
            for (int r = 0; r < 4; ++r) {
                const int row = m0 + wr * 64 + m * 16 + g * 4 + r;
                const int col = n0 + wc * 64 + n * 16 + r16;
                if (row < M) {
                    if (OUT_MODE == 1) {
                        const float v = (acc[m][n][r] + bv[n]) * oscale;
                        ((ushort_t*)Cp)[(size_t)row * 1024 + col] = f2bf(v);
                    } else {
                        ((float*)Cp)[(size_t)row * 1024 + col] = acc[m][n][r] + bv[n];
                    }
                }
            }
}

// Fused QKV projection: grid.x = 24 (8 col-tiles x 3 weights), grid.y = 32.
__global__ __launch_bounds__(256, 2)
void qkv_gemm(const ushort_t* __restrict__ qb, const ushort_t* __restrict__ kb,
              const ushort_t* __restrict__ vb,
              const ushort_t* __restrict__ Wq, const ushort_t* __restrict__ Wk,
              const ushort_t* __restrict__ Wv,
              const float* __restrict__ bq, const float* __restrict__ bk,
              const float* __restrict__ bv,
              ushort_t* __restrict__ qh, ushort_t* __restrict__ kh,
              ushort_t* __restrict__ vh)
{
    __shared__ __align__(16) ushort_t As[128 * 32];
    __shared__ __align__(16) ushort_t Bs[128 * 32];
    const int which = blockIdx.x >> 3;
    const int n0 = (blockIdx.x & 7) * 128, m0 = blockIdx.y * 128;
    const ushort_t* A; const ushort_t* Bw; const float* bias; ushort_t* dst;
    float osc = 1.f;
    if (which == 0)      { A = qb; Bw = Wq; bias = bq; dst = qh; osc = 0.125f * LOG2E; }
    else if (which == 1) { A = kb; Bw = Wk; bias = bk; dst = kh; }
    else                 { A = vb; Bw = Wv; bias = bv; dst = vh; }
    gemm_core<1>(A, Bw, bias, dst, MM, m0, n0, osc, As, Bs);
}

// Output projection: f32 out, full K, no atomics.
__global__ __launch_bounds__(256, 2)
void wo_gemm(const ushort_t* __restrict__ ctx, const ushort_t* __restrict__ Wo,
             const float* __restrict__ bo, float* __restrict__ out)
{
    __shared__ __align__(16) ushort_t As[128 * 32];
    __shared__ __align__(16) ushort_t Bs[128 * 32];
    gemm_core<0>(ctx, Wo, bo, out, MM, blockIdx.y * 128, blockIdx.x * 128, 1.f, As, Bs);
}

// ---------------------------------------------------------------------------
// vh [4000][1024] bf16 -> vhT [32 bh][64 d][2048 s] bf16 (zero-padded s)
// ---------------------------------------------------------------------------
__global__ __launch_bounds__(256)
void transpose_v(const ushort_t* __restrict__ vh, ushort_t* __restrict__ vhT)
{
    __shared__ __align__(16) ushort_t T[64 * 72];
    const int bh = blockIdx.y, b = bh >> 4, h = bh & 15;
    const int s0 = blockIdx.x * 64;
    const int t = threadIdx.x;
    #pragma unroll
    for (int i = 0; i < 2; ++i) {
        const int c = 2 * t + i, srow = c >> 3, d8 = c & 7;
        const int s = s0 + srow;
        uint4 val = make_uint4(0, 0, 0, 0);
        if (s < SS) val = *(const uint4*)(vh + (size_t)(b * SS + s) * 1024 + h * 64 + d8 * 8);
        *(uint4*)&T[srow * 72 + d8 * 8] = val;
    }
    __syncthreads();
    #pragma unroll
    for (int i = 0; i < 2; ++i) {
        const int c = 2 * t + i, drow = c >> 3, s8 = c & 7;
        ushortx8 tmp;
        #pragma unroll
        for (int j = 0; j < 8; ++j) tmp[j] = T[(s8 * 8 + j) * 72 + drow];
        *(ushortx8*)(vhT + (size_t)(bh * 64 + drow) * 2048 + s0 + s8 * 8) = tmp;
    }
}

// ---------------------------------------------------------------------------
// Fused MFMA attention v3: swapped-QK^T in-register softmax (as R10), but
// K/V staging via global_load_lds into DOUBLE-BUFFERED LDS -- no register
// prefetch (R4-R10's kreg/vreg[4] had a 32-reg live range across the whole
// tile compute and spilled to scratch: 512x256x15x128B = 252MB writes,
// matching the measured 254MB WRITE_SIZE). Linear LDS dest requires the
// both-sides XOR swizzle: global source slot = slot ^ (row&7), ds_read uses
// the same XOR (rule #21). One __syncthreads per k-tile (implicit vmcnt(0)
// drain completes the staged loads).
// ---------------------------------------------------------------------------
__global__ __launch_bounds__(256, 2)
void attn_mfma(const ushort_t* __restrict__ qh, const ushort_t* __restrict__ kh,
               const ushort_t* __restrict__ vhT, ushort_t* __restrict__ ctx,
               const int* __restrict__ c_mask, const int* __restrict__ degrees,
               const float* __restrict__ P)
{
    __shared__ __align__(16) ushort_t KsB[2][128 * 64];   // [row 128][slot 8 x 8]
    __shared__ __align__(16) ushort_t VtB[2][64 * 128];   // [d 64][slot 16 x 8]
    __shared__ uint_t kmask[64];
    __shared__ float dnm[4][32];

    const int t = threadIdx.x, l = t & 63, w = t >> 6;
    const int lo = l & 31, hi = l >> 5;
    const int bh = blockIdx.y, b = bh >> 4, h = bh & 15;
    const int qw = blockIdx.x * 128 + w * 32;
    const int sw = lo & 7;   // row-XOR swizzle key for this lane's ds_reads

    if (t < 64) {
        uint_t m = 0;
        #pragma unroll
        for (int j = 0; j < 32; ++j) {
            int idx = (t * 32 + j) / 20; idx = idx < 100 ? idx : 99;
            m |= (uint_t)(c_mask[idx] & 1) << j;
        }
        kmask[t] = m;
    }

    int qr = qw + lo; qr = qr < SS ? qr : SS - 1;
    short8 qf[4];
    {
        const ushort_t* qp = qh + (size_t)(b * SS + qr) * 1024 + h * 64 + hi * 8;
        #pragma unroll
        for (int ks = 0; ks < 4; ++ks) qf[ks] = *(const short8*)(qp + ks * 16);
    }
    const int dv = degrees[qr / KNNR];
    const float db = (P[dv * 2 + 1] - P[dv * 2 + 0]) * LOG2E;

    float denom = 0.f;
    f32x16 accO[2];
    #pragma unroll
    for (int n = 0; n < 2; ++n)
        #pragma unroll
        for (int i = 0; i < 16; ++i) accO[n][i] = 0.f;

    // Stage k-tile [kt0, kt0+128) into LDS buffer `buf` (async, no VGPRs).
    auto stage = [&](int kt0, int buf) {
        #pragma unroll
        for (int i = 0; i < 4; ++i) {                 // K: 1024 chunks of 16B
            const int c = i * 256 + w * 64 + l;
            const int row = c >> 3, slot = c & 7;
            int s = kt0 + row; s = s < SS ? s : SS - 1;
            const int gs = slot ^ (row & 7);
            const ushort_t* src = kh + (size_t)(b * SS + s) * 1024 + h * 64 + gs * 8;
            __builtin_amdgcn_global_load_lds(
                (const AS1 void*)src, (AS3 void*)&KsB[buf][(i * 256 + w * 64) * 8],
                16, 0, 0);
        }
        #pragma unroll
        for (int i = 0; i < 4; ++i) {                 // V^T: 1024 chunks of 16B
            const int c = i * 256 + w * 64 + l;
            const int d = c >> 4, slot = c & 15;
            const int gs = (slot & 8) | ((slot ^ (d & 7)) & 7);
            const ushort_t* src = vhT + (size_t)(bh * 64 + d) * 2048 + kt0 + gs * 8;
            __builtin_amdgcn_global_load_lds(
                (const AS1 void*)src, (AS3 void*)&VtB[buf][(i * 256 + w * 64) * 8],
                16, 0, 0);
        }
    };

    stage(0, 0);
    __syncthreads();                 // vmcnt(0) drain + barrier: buf0 ready

    int cur = 0;
    for (int kt = 0; kt < 16; ++kt) {
        const int kt0 = kt * 128;
        if (kt < 15) stage(kt0 + 128, cur ^ 1);   // async into other buffer

        #pragma unroll
        for (int half = 0; half < 2; ++half) {
            const int kb0 = kt0 + half * 64;

            // ---- QK^T (swapped: A=K rows, B=Q cols), swizzled ds_reads ----
            f32x16 sc[2];
            #pragma unroll
            for (int n = 0; n < 2; ++n)
                #pragma unroll
                for (int i = 0; i < 16; ++i) sc[n][i] = 0.f;
            #pragma unroll
            for (int ks = 0; ks < 4; ++ks)
                #pragma unroll
                for (int n = 0; n < 2; ++n) {
                    const int row = half * 64 + n * 32 + lo;
                    const short8 kf = *(const short8*)
                        &KsB[cur][row * 64 + ((ks * 2 + hi) ^ sw) * 8];
                    sc[n] = __builtin_amdgcn_mfma_f32_32x32x16_bf16(kf, qf[ks], sc[n], 0, 0, 0);
                }

            // ---- exp2 + bias; build PV A-fragments in registers ----
            short8 pa[4];
            #pragma unroll
            for (int n = 0; n < 2; ++n) {
                const uint_t word = kmask[(kb0 + n * 32) >> 5];
                #pragma unroll
                for (int r = 0; r < 16; ++r) {
                    const int koff = (r & 3) + 8 * (r >> 2) + 4 * hi;
                    const int kcol = kb0 + n * 32 + koff;
                    const float s = sc[n][r] + (((word >> koff) & 1u) ? db : 0.f);
                    float e = exp2f(s);
                    e = (kcol < SS) ? e : 0.f;
                    denom += e;
                    sc[n][r] = e;
                }
                uint_t w0 = cvt_pk_bf16(sc[n][0], sc[n][1]);
                uint_t w2 = cvt_pk_bf16(sc[n][4], sc[n][5]);
                plane_swap(w0, w2);
                uint_t w1 = cvt_pk_bf16(sc[n][2], sc[n][3]);
                uint_t w3 = cvt_pk_bf16(sc[n][6], sc[n][7]);
                plane_swap(w1, w3);
                uint_t u0 = cvt_pk_bf16(sc[n][8],  sc[n][9]);
                uint_t u2 = cvt_pk_bf16(sc[n][12], sc[n][13]);
                plane_swap(u0, u2);
                uint_t u1 = cvt_pk_bf16(sc[n][10], sc[n][11]);
                uint_t u3 = cvt_pk_bf16(sc[n][14], sc[n][15]);
                plane_swap(u1, u3);
                uintx4 pk0, pk1;
                pk0.x = w0; pk0.y = w1; pk0.z = w2; pk0.w = w3;
                pk1.x = u0; pk1.y = u1; pk1.z = u2; pk1.w = u3;
                pa[2 * n]     = __builtin_bit_cast(short8, pk0);
                pa[2 * n + 1] = __builtin_bit_cast(short8, pk1);
            }

            // ---- PV, swizzled ds_reads ----
            #pragma unroll
            for (int ksp = 0; ksp < 4; ++ksp)
                #pragma unroll
                for (int no = 0; no < 2; ++no) {
                    const int d = no * 32 + lo;
                    const short8 vf = *(const short8*)
                        &VtB[cur][d * 128 + (half * 8 + ((ksp * 2 + hi) ^ sw)) * 8];
                    accO[no] = __builtin_amdgcn_mfma_f32_32x32x16_bf16(pa[ksp], vf, accO[no], 0, 0, 0);
                }
        }

        __syncthreads();             // drains staged loads (vmcnt) + protects buffers
        cur ^= 1;
    }

    denom += __shfl_xor(denom, 32);
    if (hi == 0) dnm[w][lo] = denom;
    __syncthreads();

    #pragma unroll
    for (int r = 0; r < 16; ++r) {
        const int rp = (r & 3) + 8 * (r >> 2) + 4 * hi;
        const int q = qw + rp;
        if (q < SS) {
            const float inv = 1.f / dnm[w][rp];
            #pragma unroll
            for (int n = 0; n < 2; ++n)
                ctx[(size_t)(b * SS + q) * 1024 + h * 64 + n * 32 + lo] =
                    f2bf(accO[n][r] * inv);
        }
    }
}

// ---------------------------------------------------------------------------
extern "C" void kernel_launch(void* const* d_in, const int* in_sizes, int n_in,
                              void* d_out, int out_size, void* d_ws, size_t ws_size,
                              hipStream_t stream)
{
    const int*   c_mask   = (const int*)  d_in[0];
    const int*   degrees  = (const int*)  d_in[1];
    const float* q        = (const float*)d_in[2];
    const float* k        = (const float*)d_in[3];
    const float* v        = (const float*)d_in[4];
    const float* Wq       = (const float*)d_in[5];
    const float* bq       = (const float*)d_in[6];
    const float* Wk       = (const float*)d_in[7];
    const float* bk       = (const float*)d_in[8];
    const float* Wv       = (const float*)d_in[9];
    const float* bv       = (const float*)d_in[10];
    const float* Wo       = (const float*)d_in[11];
    const float* bo       = (const float*)d_in[12];
    const float* edge_emb = (const float*)d_in[13];
    const float* mask_emb = (const float*)d_in[14];
    float* out = (float*)d_out;

    char* ws = (char*)d_ws;
    const size_t MiB = 1024 * 1024;
    ushort_t* qb   = (ushort_t*)(ws + 0 * MiB);
    ushort_t* kb_  = (ushort_t*)(ws + 8 * MiB);
    ushort_t* vb_  = (ushort_t*)(ws + 16 * MiB);
    ushort_t* Wqb  = (ushort_t*)(ws + 24 * MiB);
    ushort_t* Wkb  = (ushort_t*)(ws + 26 * MiB);
    ushort_t* Wvb  = (ushort_t*)(ws + 28 * MiB);
    ushort_t* Wob  = (ushort_t*)(ws + 30 * MiB);
    ushort_t* qhB  = (ushort_t*)(ws + 32 * MiB);
    ushort_t* khB  = (ushort_t*)(ws + 40 * MiB);
    ushort_t* vhB  = (ushort_t*)(ws + 48 * MiB);
    float*    P    = (float*)   (ws + 56 * MiB);
    ushort_t* vhT  = kb_;   // kb consumed by QKV GEMM before transpose runs
    ushort_t* ctx  = qb;    // qb consumed by QKV GEMM before attn runs

    cvt3_kernel<<<dim3(1024, 3), 256, 0, stream>>>(q, k, v, qb, kb_, vb_, MM * HIDDEN);
    cvt4_kernel<<<dim3(1024, 4), 256, 0, stream>>>(Wq, Wk, Wv, Wo, Wqb, Wkb, Wvb, Wob,
                                                   HIDDEN * HIDDEN);
    bias_table_kernel<<<dim3(128), dim3(64), 0, stream>>>(edge_emb, mask_emb, P);

    qkv_gemm<<<dim3(24, 32), 256, 0, stream>>>(qb, kb_, vb_, Wqb, Wkb, Wvb,
                                               bq, bk, bv, qhB, khB, vhB);

    transpose_v<<<dim3(32, 32), 256, 0, stream>>>(vhB, vhT);

    attn_mfma<<<dim3(16, 32), 256, 0, stream>>>(qhB, khB, vhT, ctx, c_mask, degrees, P);

    wo_gemm<<<dim3(8, 32), 256, 0, stream>>>(ctx, Wob, bo, out);
}